// Round 1
// baseline (590.192 us; speedup 1.0000x reference)
//
#include <hip/hip_runtime.h>
#include <hip/hip_bf16.h>

// GRU teacher-forced NLL, B=8192, S=2048, H=8, IN_DIM=4, NCLS=10.
// Strategy: 8 lanes per batch element (65536 threads = 1 wave/SIMD machine-wide).
// Lane i owns hidden component i; h replicated per-lane via DPP/swizzle butterfly
// all-gather; per-lane weight rows PRE-PERMUTED to the gather order (reg m of the
// gather holds h[i^m], so lane i loads W[i][i^m] into reg m).
// All gate pre-activations prescaled by log2(e) (2*log2(e) for tanh) so the
// nonlinearities are raw v_exp_f32/v_rcp_f32; log-softmax in base-2, scaled by ln2
// once at the end. Input-side matmuls are a 10-entry LDS lookup table.

#define SEQ   2048
#define BATCH 8192

static __device__ __forceinline__ float xor1f(float x) {
    int r = __builtin_amdgcn_update_dpp(__builtin_bit_cast(int, x),
                                        __builtin_bit_cast(int, x),
                                        0xB1 /*quad_perm [1,0,3,2]*/, 0xF, 0xF, true);
    return __builtin_bit_cast(float, r);
}
static __device__ __forceinline__ float xor2f(float x) {
    int r = __builtin_amdgcn_update_dpp(__builtin_bit_cast(int, x),
                                        __builtin_bit_cast(int, x),
                                        0x4E /*quad_perm [2,3,0,1]*/, 0xF, 0xF, true);
    return __builtin_bit_cast(float, r);
}
static __device__ __forceinline__ float xor4f(float x) {
    // ds_swizzle BitMode: offset = (xor=4)<<10 | (or=0)<<5 | (and=0x1F) = 0x101F
    int r = __builtin_amdgcn_ds_swizzle(__builtin_bit_cast(int, x), 0x101F);
    return __builtin_bit_cast(float, r);
}

__global__ __launch_bounds__(256, 1)
void gru_nll_kernel(const int* __restrict__ xb,
                    const float* __restrict__ Wir, const float* __restrict__ bir,
                    const float* __restrict__ Wiz, const float* __restrict__ biz,
                    const float* __restrict__ Win, const float* __restrict__ bin_,
                    const float* __restrict__ Whr, const float* __restrict__ bhr,
                    const float* __restrict__ Whz, const float* __restrict__ bhz,
                    const float* __restrict__ Whn, const float* __restrict__ bhn,
                    const float* __restrict__ Wout, const float* __restrict__ bout,
                    float* __restrict__ out)
{
    constexpr float S1 = 1.4426950408889634f;   // log2(e)
    // gi tables: [gate][count(10) * 9 + i], stride 9 floats per count to spread banks
    __shared__ float gi[3 * 90];
    __shared__ float red[256];

    const int tid = threadIdx.x;

    // ---- build input-contribution tables (counts 0..9, comps 0..7) ----
    if (tid < 80) {
        int c = tid >> 3, i = tid & 7;
        // powers = [8,4,2,1] MSB-first -> Wi columns 0..3
        float b0 = (float)((c >> 3) & 1);
        float b1 = (float)((c >> 2) & 1);
        float b2 = (float)((c >> 1) & 1);
        float b3 = (float)(c & 1);
        float gr = bir[i] + bhr[i]
                 + b0 * Wir[i*4+0] + b1 * Wir[i*4+1] + b2 * Wir[i*4+2] + b3 * Wir[i*4+3];
        float gz = biz[i] + bhz[i]
                 + b0 * Wiz[i*4+0] + b1 * Wiz[i*4+1] + b2 * Wiz[i*4+2] + b3 * Wiz[i*4+3];
        float gn = bin_[i]
                 + b0 * Win[i*4+0] + b1 * Win[i*4+1] + b2 * Win[i*4+2] + b3 * Win[i*4+3];
        gi[      c*9 + i] = S1 * gr;
        gi[ 90 + c*9 + i] = S1 * gz;
        gi[180 + c*9 + i] = 2.0f * S1 * gn;   // tanh gate scaled by 2*log2(e)
    }

    const int lane = tid & 63;
    const int i    = tid & 7;                     // hidden component owned
    const int b    = blockIdx.x * 32 + (tid >> 3); // batch element

    // ---- per-lane constant registers, permuted to gather order ----
    float whr[8], whz[8], whn[8], wA[8], wB[8];
    #pragma unroll
    for (int m = 0; m < 8; ++m) {
        int col = i ^ m;
        whr[m] = S1 * Whr[i*8 + col];
        whz[m] = S1 * Whz[i*8 + col];
        whn[m] = 2.0f * S1 * Whn[i*8 + col];
        wA[m]  = S1 * Wout[i*8 + col];
        wB[m]  = (i < 2) ? S1 * Wout[(8+i)*8 + col] : 0.0f;
    }
    const float ghn_b = 2.0f * S1 * bhn[i];
    const float bA    = S1 * bout[i];
    const float bB    = (i < 2) ? S1 * bout[8+i] : -1e30f;  // exp2(-1e30) == 0

    __syncthreads();

    const int4* row4 = (const int4*)(xb + (size_t)b * SEQ);

    float h[8];
    #pragma unroll
    for (int m = 0; m < 8; ++m) h[m] = 0.0f;
    float acc = 0.0f;
    int   cin = 0;

    const float* giR = gi;
    const float* giZ = gi + 90;
    const float* giN = gi + 180;

    auto step = [&](int c_in, int t) {
        int gidx = c_in * 9 + i;
        float ar = giR[gidx];
        float az = giZ[gidx];
        float u0 = giN[gidx];
        float hn = ghn_b;
        #pragma unroll
        for (int m = 0; m < 8; ++m) {
            ar = __builtin_fmaf(whr[m], h[m], ar);
            az = __builtin_fmaf(whz[m], h[m], az);
            hn = __builtin_fmaf(whn[m], h[m], hn);
        }
        // r,z = sigmoid (prescaled): 1/(1+2^-a)
        float r = __builtin_amdgcn_rcpf(1.0f + __builtin_amdgcn_exp2f(-ar));
        float z = __builtin_amdgcn_rcpf(1.0f + __builtin_amdgcn_exp2f(-az));
        // n = tanh(v), u = 2*log2e*v: 1 - 2/(2^u + 1)
        float u = __builtin_fmaf(r, hn, u0);
        float n = __builtin_fmaf(-2.0f,
                    __builtin_amdgcn_rcpf(1.0f + __builtin_amdgcn_exp2f(u)), 1.0f);
        float hnew = __builtin_fmaf(z, h[0] - n, n);   // h[0] = own old h_i
        // butterfly all-gather: reg m <- h[(lane^m)&7]
        h[0] = hnew;
        h[1] = xor1f(h[0]);
        h[2] = xor2f(h[0]);
        h[3] = xor2f(h[1]);
        h[4] = xor4f(h[0]);
        h[5] = xor4f(h[1]);
        h[6] = xor4f(h[2]);
        h[7] = xor4f(h[3]);
        // logits (prescaled by log2e): lane i -> class i (A) and class 8+i (B, i<2)
        float lA = bA, lB = bB;
        #pragma unroll
        for (int m = 0; m < 8; ++m) {
            lA = __builtin_fmaf(wA[m], h[m], lA);
            lB = __builtin_fmaf(wB[m], h[m], lB);
        }
        float s = __builtin_amdgcn_exp2f(lA) + __builtin_amdgcn_exp2f(lB);
        s += xor1f(s);
        s += xor2f(s);
        s += xor4f(s);
        // target logit: class t lives in lane (t&7), reg A if t<8 else reg B
        float lsend = (t >= 8) ? lB : lA;
        float lt = __shfl(lsend, (lane & 56) | (t & 7), 64);
        acc += __builtin_amdgcn_logf(s) - lt;   // base-2 logsumexp - logit'
    };

    int4 cc = row4[0];
    for (int jb = 0; jb < SEQ/4; ++jb) {
        int nidx = (jb + 1 < SEQ/4) ? (jb + 1) : jb;
        int4 nx = row4[nidx];               // prefetch next 4 counts
        step(cin,  cc.x);
        step(cc.x, cc.y);
        step(cc.y, cc.z);
        step(cc.z, cc.w);
        cin = cc.w;
        cc = nx;
    }

    // ---- block reduction, then one atomic per block ----
    red[tid] = acc;
    __syncthreads();
    #pragma unroll
    for (int sft = 128; sft > 0; sft >>= 1) {
        if (tid < sft) red[tid] += red[tid + sft];
        __syncthreads();
    }
    if (tid == 0) {
        // acc is in base-2 units, duplicated x8 per element; final = ln2 * sum/(8*B*S)
        constexpr float SCALE =
            (float)(0.69314718055994530942 / (8.0 * 8192.0 * 2048.0));
        atomicAdd(out, red[0] * SCALE);
    }
}

extern "C" void kernel_launch(void* const* d_in, const int* in_sizes, int n_in,
                              void* d_out, int out_size, void* d_ws, size_t ws_size,
                              hipStream_t stream) {
    // d_out is re-poisoned (0xAA) before every timed replay -> zero it ourselves.
    hipMemsetAsync(d_out, 0, sizeof(float), stream);
    gru_nll_kernel<<<BATCH * 8 / 256, 256, 0, stream>>>(
        (const int*)d_in[0],
        (const float*)d_in[1],  (const float*)d_in[2],
        (const float*)d_in[3],  (const float*)d_in[4],
        (const float*)d_in[5],  (const float*)d_in[6],
        (const float*)d_in[7],  (const float*)d_in[8],
        (const float*)d_in[9],  (const float*)d_in[10],
        (const float*)d_in[11], (const float*)d_in[12],
        (const float*)d_in[13], (const float*)d_in[14],
        (float*)d_out);
}

// Round 2
// 461.586 us; speedup vs baseline: 1.2786x; 1.2786x over previous
//
#include <hip/hip_runtime.h>
#include <hip/hip_bf16.h>

// GRU teacher-forced NLL, B=8192, S=2048, H=8, IN_DIM=4, NCLS=10.
// 8 lanes per batch element (65536 threads = 1 wave/SIMD machine-wide).
// Lane i owns hidden component i. h replicated per-lane via ALL-DPP butterfly:
// quad_perm xor1/xor2 + ROW_HALF_MIRROR (lane-xor-7 within the 8-lane group),
// giving gather window perm = [0,1,2,3,7,6,5,4]; weight rows are PRE-PERMUTED
// to this order (reg m of lane i holds W[row][i ^ perm[m]]).
// Gate pre-activations prescaled by log2(e) (2*log2(e) for tanh) so all
// nonlinearities are raw v_exp_f32/v_rcp_f32; log-softmax in base 2, one ln2
// scale at the end. Input-side matmuls: 10-entry LDS float4 table, PREFETCHED
// one step ahead (next input == current target). Dot products in packed f32
// (v_pk_fma_f32) with 2-accumulator trees. Target-logit fetch replaced by an
// ownership predicate (lane i==t&7 contributes -8*logit; /8 folded in SCALE).

#define SEQ   2048
#define BATCH 8192

typedef float f2 __attribute__((ext_vector_type(2)));

static __device__ __forceinline__ float xor1f(float x) {
    int r = __builtin_amdgcn_update_dpp(__builtin_bit_cast(int, x),
                                        __builtin_bit_cast(int, x),
                                        0xB1 /*quad_perm [1,0,3,2]*/, 0xF, 0xF, true);
    return __builtin_bit_cast(float, r);
}
static __device__ __forceinline__ float xor2f(float x) {
    int r = __builtin_amdgcn_update_dpp(__builtin_bit_cast(int, x),
                                        __builtin_bit_cast(int, x),
                                        0x4E /*quad_perm [2,3,0,1]*/, 0xF, 0xF, true);
    return __builtin_bit_cast(float, r);
}
static __device__ __forceinline__ float hmf(float x) {
    // ROW_HALF_MIRROR: lane -> lane ^ 7 within each 8-lane half-row
    int r = __builtin_amdgcn_update_dpp(__builtin_bit_cast(int, x),
                                        __builtin_bit_cast(int, x),
                                        0x141, 0xF, 0xF, true);
    return __builtin_bit_cast(float, r);
}

__global__ __launch_bounds__(256, 1)
void gru_nll_kernel(const int* __restrict__ xb,
                    const float* __restrict__ Wir, const float* __restrict__ bir,
                    const float* __restrict__ Wiz, const float* __restrict__ biz,
                    const float* __restrict__ Win, const float* __restrict__ bin_,
                    const float* __restrict__ Whr, const float* __restrict__ bhr,
                    const float* __restrict__ Whz, const float* __restrict__ bhz,
                    const float* __restrict__ Whn, const float* __restrict__ bhn,
                    const float* __restrict__ Wout, const float* __restrict__ bout,
                    float* __restrict__ out)
{
    constexpr float S1 = 1.4426950408889634f;   // log2(e)
    // gi table: [count][row] float4 {ar0, az0, u0, pad}; count stride 36 floats
    // (16B aligned, staggers banks by 4 per count)
    __shared__ float gi[10 * 36];
    __shared__ float red[256];

    const int tid = threadIdx.x;

    if (tid < 80) {
        int c = tid >> 3, ii = tid & 7;
        float b0 = (float)((c >> 3) & 1);
        float b1 = (float)((c >> 2) & 1);
        float b2 = (float)((c >> 1) & 1);
        float b3 = (float)(c & 1);
        float gr = bir[ii] + bhr[ii]
                 + b0*Wir[ii*4+0] + b1*Wir[ii*4+1] + b2*Wir[ii*4+2] + b3*Wir[ii*4+3];
        float gz = biz[ii] + bhz[ii]
                 + b0*Wiz[ii*4+0] + b1*Wiz[ii*4+1] + b2*Wiz[ii*4+2] + b3*Wiz[ii*4+3];
        float gn = bin_[ii]
                 + b0*Win[ii*4+0] + b1*Win[ii*4+1] + b2*Win[ii*4+2] + b3*Win[ii*4+3];
        float* e = &gi[c*36 + ii*4];
        e[0] = S1 * gr;
        e[1] = S1 * gz;
        e[2] = 2.0f * S1 * gn;
        e[3] = 0.0f;
    }

    const int i = tid & 7;                       // hidden component owned
    const int b = blockIdx.x * 32 + (tid >> 3);  // batch element

    // gather-order permutation for the all-DPP butterfly
    const int perm[8] = {0, 1, 2, 3, 7, 6, 5, 4};

    f2 whrP[4], whzP[4], whnP[4], wAP[4], wBP[4];
    #pragma unroll
    for (int p = 0; p < 4; ++p) {
        int c0 = i ^ perm[2*p], c1 = i ^ perm[2*p+1];
        whrP[p] = f2{S1 * Whr[i*8 + c0],        S1 * Whr[i*8 + c1]};
        whzP[p] = f2{S1 * Whz[i*8 + c0],        S1 * Whz[i*8 + c1]};
        whnP[p] = f2{2.0f*S1 * Whn[i*8 + c0],   2.0f*S1 * Whn[i*8 + c1]};
        wAP[p]  = f2{S1 * Wout[i*8 + c0],       S1 * Wout[i*8 + c1]};
        wBP[p]  = (i < 2) ? f2{S1 * Wout[(8+i)*8 + c0], S1 * Wout[(8+i)*8 + c1]}
                          : f2{0.0f, 0.0f};
    }
    const float ghn_b = 2.0f * S1 * bhn[i];
    const float bA    = S1 * bout[i];
    const float bB    = (i < 2) ? S1 * bout[8+i] : -1e30f;  // exp2(-1e30) == 0

    __syncthreads();

    const int4* row4 = (const int4*)(xb + (size_t)b * SEQ);

    f2 H[4];
    #pragma unroll
    for (int p = 0; p < 4; ++p) H[p] = f2{0.0f, 0.0f};
    float acc = 0.0f;

    // table entry for the current step's input (first input = 0)
    float4 g = *(const float4*)&gi[0*36 + (i << 2)];

    auto step = [&](int t) {
        // prefetch next step's table entry (next input == this step's target)
        float4 gn = *(const float4*)&gi[t*36 + (i << 2)];

        f2 arP = f2{g.x, 0.0f}, azP = f2{g.y, 0.0f}, hnP = f2{ghn_b, 0.0f};
        #pragma unroll
        for (int p = 0; p < 4; ++p) {
            arP += whrP[p] * H[p];
            azP += whzP[p] * H[p];
            hnP += whnP[p] * H[p];
        }
        float ar = arP.x + arP.y;
        float az = azP.x + azP.y;
        float hn = hnP.x + hnP.y;

        float r = __builtin_amdgcn_rcpf(1.0f + __builtin_amdgcn_exp2f(-ar));
        float z = __builtin_amdgcn_rcpf(1.0f + __builtin_amdgcn_exp2f(-az));
        float u = __builtin_fmaf(r, hn, g.z);
        float n = __builtin_fmaf(-2.0f,
                    __builtin_amdgcn_rcpf(1.0f + __builtin_amdgcn_exp2f(u)), 1.0f);
        float h0   = H[0].x;                       // own previous h_i
        float hnew = __builtin_fmaf(z, h0 - n, n);

        // all-DPP butterfly: reg m <- h[i ^ perm[m]]
        float v0 = hnew;
        float v1 = xor1f(v0);
        float v2 = xor2f(v0);
        float v3 = xor2f(v1);
        float v4 = hmf(v0);     // h[i^7]
        float v5 = hmf(v1);     // h[i^6]
        float v6 = hmf(v2);     // h[i^5]
        float v7 = hmf(v3);     // h[i^4]
        H[0] = f2{v0, v1}; H[1] = f2{v2, v3}; H[2] = f2{v4, v5}; H[3] = f2{v6, v7};

        f2 lAP = f2{bA, 0.0f}, lBP = f2{bB, 0.0f};
        #pragma unroll
        for (int p = 0; p < 4; ++p) {
            lAP += wAP[p] * H[p];
            lBP += wBP[p] * H[p];
        }
        float lA = lAP.x + lAP.y;
        float lB = lBP.x + lBP.y;

        float s = __builtin_amdgcn_exp2f(lA) + __builtin_amdgcn_exp2f(lB);
        s += xor1f(s);
        s += xor2f(s);
        s += hmf(s);            // quad-sums are quad-uniform, so xor7 == xor4 here
        acc += __builtin_amdgcn_logf(s);   // log2

        // ownership: lane i == t&7 holds class t's logit (A if t<8, B if t>=8)
        float sel = (t >= 8) ? lB : lA;
        if ((t & 7) == i) acc = __builtin_fmaf(-8.0f, sel, acc);

        g = gn;
    };

    int4 cc = row4[0];
    for (int jb = 0; jb < SEQ/4; ++jb) {
        int nidx = (jb + 1 < SEQ/4) ? (jb + 1) : jb;
        int4 nx = row4[nidx];               // prefetch next 4 counts
        step(cc.x);
        step(cc.y);
        step(cc.z);
        step(cc.w);
        cc = nx;
    }

    red[tid] = acc;
    __syncthreads();
    #pragma unroll
    for (int sft = 128; sft > 0; sft >>= 1) {
        if (tid < sft) red[tid] += red[tid + sft];
        __syncthreads();
    }
    if (tid == 0) {
        // acc in base-2 units, x8 lane duplication; final = ln2 * sum / (8*B*S)
        constexpr float SCALE =
            (float)(0.69314718055994530942 / (8.0 * 8192.0 * 2048.0));
        atomicAdd(out, red[0] * SCALE);
    }
}

extern "C" void kernel_launch(void* const* d_in, const int* in_sizes, int n_in,
                              void* d_out, int out_size, void* d_ws, size_t ws_size,
                              hipStream_t stream) {
    hipMemsetAsync(d_out, 0, sizeof(float), stream);
    gru_nll_kernel<<<BATCH * 8 / 256, 256, 0, stream>>>(
        (const int*)d_in[0],
        (const float*)d_in[1],  (const float*)d_in[2],
        (const float*)d_in[3],  (const float*)d_in[4],
        (const float*)d_in[5],  (const float*)d_in[6],
        (const float*)d_in[7],  (const float*)d_in[8],
        (const float*)d_in[9],  (const float*)d_in[10],
        (const float*)d_in[11], (const float*)d_in[12],
        (const float*)d_in[13], (const float*)d_in[14],
        (float*)d_out);
}